// Round 2
// 395.595 us; speedup vs baseline: 1.0044x; 1.0044x over previous
//
#include <hip/hip_runtime.h>
#include <hip/hip_bf16.h>

// Problem constants (B,R,M,L,H) = (256, 2048, 65536, 64, 4)
#define BB   256
#define RR   2048
#define MM   65536
#define LL   64
#define HH   4
#define NROW 1024      // B*H rows
#define KEYS 256       // H*L

typedef float f32x4 __attribute__((ext_vector_type(4)));
typedef short short8 __attribute__((ext_vector_type(8)));

#define MFMA(A,B,C) __builtin_amdgcn_mfma_f32_16x16x32_bf16((A),(B),(C),0,0,0)
#define LOG2E 1.4426950408889634f
#define EXP2F(x) __builtin_amdgcn_exp2f(x)

// ---- bf16 round-nearest-even split helpers ----
__device__ __forceinline__ unsigned short bf16_rn(float x) {
    union { float f; unsigned int u; } v; v.f = x;
    unsigned int r = v.u + 0x7FFFu + ((v.u >> 16) & 1u);
    return (unsigned short)(r >> 16);
}
__device__ __forceinline__ float bf16_to_f(unsigned short h) {
    union { float f; unsigned int u; } v; v.u = ((unsigned int)h) << 16; return v.f;
}
__device__ __forceinline__ void split8_store(const float* x, unsigned short* hi, unsigned short* lo) {
    unsigned int ph[4], pl[4];
#pragma unroll
    for (int j = 0; j < 4; ++j) {
        unsigned short h0 = bf16_rn(x[2*j]),   l0 = bf16_rn(x[2*j]   - bf16_to_f(h0));
        unsigned short h1 = bf16_rn(x[2*j+1]), l1 = bf16_rn(x[2*j+1] - bf16_to_f(h1));
        ph[j] = (unsigned int)h0 | ((unsigned int)h1 << 16);
        pl[j] = (unsigned int)l0 | ((unsigned int)l1 << 16);
    }
    ((uint4*)hi)[0] = make_uint4(ph[0], ph[1], ph[2], ph[3]);
    ((uint4*)lo)[0] = make_uint4(pl[0], pl[1], pl[2], pl[3]);
}

// ---------------- generic 64x64 tiled transpose: out[c][r] = in[r][c] ----------------
__global__ __launch_bounds__(256) void transpose_k(const float* __restrict__ in,
                                                   float* __restrict__ out,
                                                   int NR, int NC) {
    __shared__ float t[64 * 65];
    int r0 = blockIdx.x * 64, c0 = blockIdx.y * 64;
    int lane = threadIdx.x & 63, w = threadIdx.x >> 6;
#pragma unroll
    for (int i = 0; i < 16; ++i) {
        int rr = i * 4 + w;
        t[lane * 65 + rr] = in[(size_t)(r0 + rr) * NC + c0 + lane];
    }
    __syncthreads();
#pragma unroll
    for (int i = 0; i < 16; ++i) {
        int cc = i * 4 + w;
        out[(size_t)(c0 + cc) * NR + r0 + lane] = t[cc * 65 + lane];
    }
}

// ---------------- fused: stage 128 mem rows in LDS (coalesced), emit MFMA B-fragments
//                  (hi/lo bf16 split) + per-block max row squared-norm ----------------
// grid 512 blocks x 256 thr; block handles rows [blk*128, blk*128+128)
// frag_id = t*2 + c ; global t = blk*8 + t_local
__global__ __launch_bounds__(256) void prep_mem(const float* __restrict__ mem,
                                                unsigned short* __restrict__ bhi,
                                                unsigned short* __restrict__ blo,
                                                float* __restrict__ normpart) {
    __shared__ float t[128 * 68];     // pad 68: keeps float4 alignment, spreads banks
    __shared__ float rowsq[128];
    int blk = blockIdx.x, tid = threadIdx.x;
    const f32x4* src = (const f32x4*)(mem + (size_t)blk * 128 * LL);
    // coalesced stage: 2048 float4, 8 per thread
#pragma unroll
    for (int i = 0; i < 8; ++i) {
        int idx = i * 256 + tid;              // flat float4 index
        int row = idx >> 4, c4 = idx & 15;
        *(f32x4*)&t[row * 68 + c4 * 4] = src[idx];
    }
    __syncthreads();
    // per-row squared norm
    if (tid < 128) {
        const float* rp = t + tid * 68;
        float s = 0.f;
#pragma unroll
        for (int k = 0; k < 64; ++k) s = fmaf(rp[k], rp[k], s);
        rowsq[tid] = s;
    }
    __syncthreads();
    if (tid < 64) {
        float m = fmaxf(rowsq[tid], rowsq[tid + 64]);
#pragma unroll
        for (int off = 1; off < 64; off <<= 1) m = fmaxf(m, __shfl_xor(m, off, 64));
        if (tid == 0) normpart[blk] = m;
    }
    // fragment gather + split:  16 frags x 64 lanes = 1024 slots, 4 per thread
#pragma unroll
    for (int i = 0; i < 4; ++i) {
        int slot = i * 256 + tid;
        int lane = slot & 63, frag_l = slot >> 6;   // frag_l 0..15
        int t_l = frag_l >> 1, c = frag_l & 1;
        int row = t_l * 16 + (lane & 15);
        int k0 = c * 32 + (lane >> 4) * 8;
        const float* p = t + row * 68 + k0;
        float x[8];
#pragma unroll
        for (int j = 0; j < 8; ++j) x[j] = p[j];
        size_t gslot = ((size_t)blk * 16 + frag_l) * 64 + lane;
        split8_store(x, bhi + gslot * 8, blo + gslot * 8);
    }
}

// ---------------- K0: split-k partial keys GEMM ----------------
__global__ __launch_bounds__(256) void k0_keys(const float* __restrict__ S,
                                               const float* __restrict__ WkT,
                                               float* __restrict__ kpart) {
    __shared__ float sl[8 * 256];
    int bg = blockIdx.x, kc = blockIdx.y, tid = threadIdx.x;
    int b0 = bg * 8;
#pragma unroll
    for (int bi = 0; bi < 8; ++bi)
        sl[bi * 256 + tid] = S[(size_t)(b0 + bi) * RR + kc * 256 + tid];
    __syncthreads();
    float acc[8] = {0,0,0,0,0,0,0,0};
    const float* wp = WkT + (size_t)kc * 256 * KEYS + tid;
#pragma unroll 4
    for (int kk = 0; kk < 256; ++kk) {
        float wv = wp[kk * KEYS];
#pragma unroll
        for (int bi = 0; bi < 8; ++bi)
            acc[bi] = fmaf(sl[bi * 256 + kk], wv, acc[bi]);
    }
    float* op = kpart + (size_t)kc * BB * KEYS + (size_t)b0 * KEYS + tid;
#pragma unroll
    for (int bi = 0; bi < 8; ++bi)
        op[bi * KEYS] = acc[bi];
}

// ---------------- K1: beta, key norm, q_rm = keys*beta*log2e/norm, brow = beta*maxnorm*log2e ----
__global__ __launch_bounds__(256) void k1_finalize(const float* __restrict__ S,
                                                   const float* __restrict__ kpart,
                                                   const float* __restrict__ bk,
                                                   const float* __restrict__ Wb,
                                                   const float* __restrict__ bb,
                                                   const float* __restrict__ normpart,
                                                   float* __restrict__ q_rm,
                                                   float* __restrict__ brow) {
    int bh = blockIdx.x, b = bh >> 2, h = bh & 3;
    int tid = threadIdx.x, lane = tid & 63, w = tid >> 6;
    float p = 0.f;
#pragma unroll
    for (int i = 0; i < 8; ++i) {
        int k = i * 256 + tid;
        p += S[(size_t)b * RR + k] * Wb[(size_t)h * RR + k];
    }
    float nm = fmaxf(normpart[tid], normpart[256 + tid]);   // 512 partials
#pragma unroll
    for (int off = 1; off < 64; off <<= 1) {
        p  += __shfl_xor(p, off, 64);
        nm  = fmaxf(nm, __shfl_xor(nm, off, 64));
    }
    __shared__ float red[4], redm[4];
    if (lane == 0) { red[w] = p; redm[w] = nm; }
    __syncthreads();
    if (tid < 64) {
        float beta = red[0] + red[1] + red[2] + red[3] + bb[h];
        beta = fmaxf(beta, 0.f);
        float maxn = sqrtf(fmaxf(fmaxf(redm[0], redm[1]), fmaxf(redm[2], redm[3])));
        float kv = bk[h * LL + lane];
#pragma unroll
        for (int c = 0; c < 8; ++c)
            kv += kpart[(size_t)c * BB * KEYS + (size_t)b * KEYS + h * LL + lane];
        float sq = kv * kv;
#pragma unroll
        for (int off = 1; off < 64; off <<= 1) sq += __shfl_xor(sq, off, 64);
        float scale = beta * LOG2E / sqrtf(sq);
        q_rm[(size_t)bh * LL + lane] = kv * scale;
        if (lane == 0) brow[bh] = beta * maxn * LOG2E;  // exact upper bound (Cauchy-Schwarz), log2 domain
    }
}

// ---------------- swizzle q into MFMA A-fragment order, hi/lo bf16 ----------------
__global__ __launch_bounds__(256) void prep_a(const float* __restrict__ q_rm,
                                              unsigned short* __restrict__ ahi,
                                              unsigned short* __restrict__ alo) {
    int gid = blockIdx.x * 256 + threadIdx.x;   // 0..8191
    int lane = gid & 63, frag = gid >> 6;       // frag 0..127
    int rtg = frag >> 1, c = frag & 1;
    int row = rtg * 16 + (lane & 15);
    int k0 = c * 32 + (lane >> 4) * 8;
    const float4* src = (const float4*)(q_rm + (size_t)row * LL + k0);
    float4 x0 = src[0], x1 = src[1];
    float x[8] = {x0.x, x0.y, x0.z, x0.w, x1.x, x1.y, x1.z, x1.w};
    split8_store(x, ahi + (size_t)gid * 8, alo + (size_t)gid * 8);
}

// XCD-chunked bijective swizzle for 1024 blocks (1024 % 8 == 0):
// all 16 rg-blocks of one mblk land on ONE XCD -> B slice (262KB) L2-resident,
// 8 mblk * 262KB = 2.1MB per XCD L2 (4MB).
__device__ __forceinline__ void decode_wg(int bx, int& mblk, int& rg) {
    int wg = ((bx & 7) << 7) | (bx >> 3);
    mblk = wg >> 4; rg = wg & 15;
}

// ---------------- K2: split-bf16 MFMA dot + exp2(d - brow) partial row sums ----------
__global__ __launch_bounds__(256) void k2_mfma(const unsigned short* __restrict__ bhi,
                                               const unsigned short* __restrict__ blo,
                                               const unsigned short* __restrict__ ahi,
                                               const unsigned short* __restrict__ alo,
                                               const float* __restrict__ brow,
                                               float* __restrict__ psum) {
    int mblk, rg; decode_wg(blockIdx.x, mblk, rg);
    int tid = threadIdx.x, w = tid >> 6, lane = tid & 63;
    int g = lane >> 4;
    short8 Ah[4][2], Al[4][2];
#pragma unroll
    for (int rt = 0; rt < 4; ++rt)
#pragma unroll
        for (int c = 0; c < 2; ++c) {
            size_t off = ((size_t)((rg * 4 + rt) * 2 + c) * 64 + lane) * 8;
            Ah[rt][c] = *(const short8*)(ahi + off);
            Al[rt][c] = *(const short8*)(alo + off);
        }
    float br[4][4];
#pragma unroll
    for (int rt = 0; rt < 4; ++rt)
#pragma unroll
        for (int r = 0; r < 4; ++r)
            br[rt][r] = brow[rg * 64 + rt * 16 + g * 4 + r];
    float s[4][4] = {{0.f}};
    int t0 = mblk * 64 + w * 16;
    // 1-deep register prefetch of B fragments
    short8 Bh0, Bh1, Bl0, Bl1;
    {
        size_t o = (size_t)t0 * 1024 + (size_t)lane * 8;
        Bh0 = *(const short8*)(bhi + o); Bh1 = *(const short8*)(bhi + o + 512);
        Bl0 = *(const short8*)(blo + o); Bl1 = *(const short8*)(blo + o + 512);
    }
#pragma unroll 4
    for (int ti = 0; ti < 16; ++ti) {
        int tn = t0 + ((ti < 15) ? ti + 1 : 15);      // clamp: harmless re-load on last iter
        size_t on = (size_t)tn * 1024 + (size_t)lane * 8;
        short8 nh0 = *(const short8*)(bhi + on);
        short8 nh1 = *(const short8*)(bhi + on + 512);
        short8 nl0 = *(const short8*)(blo + on);
        short8 nl1 = *(const short8*)(blo + on + 512);
#pragma unroll
        for (int rt = 0; rt < 4; ++rt) {
            f32x4 C = {0.f, 0.f, 0.f, 0.f};
            C = MFMA(Ah[rt][0], Bh0, C);
            C = MFMA(Ah[rt][1], Bh1, C);
            C = MFMA(Al[rt][0], Bh0, C);
            C = MFMA(Al[rt][1], Bh1, C);
            C = MFMA(Ah[rt][0], Bl0, C);
            C = MFMA(Ah[rt][1], Bl1, C);
#pragma unroll
            for (int r = 0; r < 4; ++r)
                s[rt][r] += EXP2F(C[r] - br[rt][r]);
        }
        Bh0 = nh0; Bh1 = nh1; Bl0 = nl0; Bl1 = nl1;
    }
#pragma unroll
    for (int rt = 0; rt < 4; ++rt)
#pragma unroll
        for (int r = 0; r < 4; ++r) {
            float v = s[rt][r];
            v += __shfl_xor(v, 1, 64);
            v += __shfl_xor(v, 2, 64);
            v += __shfl_xor(v, 4, 64);
            v += __shfl_xor(v, 8, 64);
            s[rt][r] = v;
        }
    if ((lane & 15) == 0) {
        int col = mblk * 4 + w;
#pragma unroll
        for (int rt = 0; rt < 4; ++rt)
#pragma unroll
            for (int r = 0; r < 4; ++r) {
                int row = rg * 64 + rt * 16 + g * 4 + r;
                psum[(size_t)row * 256 + col] = s[rt][r];
            }
    }
}

// ---------------- K3: combine 256 partial sums per row -> 1/sum ----------------
__global__ __launch_bounds__(256) void k3_combine(const float* __restrict__ psum,
                                                  float* __restrict__ ginv) {
    int row = blockIdx.x, tid = threadIdx.x, lane = tid & 63, w = tid >> 6;
    float v = psum[(size_t)row * 256 + tid];
#pragma unroll
    for (int off = 1; off < 64; off <<= 1) v += __shfl_xor(v, off, 64);
    __shared__ float sm[4];
    if (lane == 0) sm[w] = v;
    __syncthreads();
    if (tid == 0) ginv[row] = 1.0f / (sm[0] + sm[1] + sm[2] + sm[3]);
}

// ---------------- K4: recompute dots via MFMA, LDS-staged coalesced float4 nt stores ----
__global__ __launch_bounds__(256) void k4_mfma(const unsigned short* __restrict__ bhi,
                                               const unsigned short* __restrict__ blo,
                                               const unsigned short* __restrict__ ahi,
                                               const unsigned short* __restrict__ alo,
                                               const float* __restrict__ brow,
                                               const float* __restrict__ ginv,
                                               float* __restrict__ out) {
    __shared__ float ot[4][64 * 20];   // per-wave 64 rows x 16 cols, pad 20 (2-way max)
    int mblk, rg; decode_wg(blockIdx.x, mblk, rg);
    int tid = threadIdx.x, w = tid >> 6, lane = tid & 63;
    int g = lane >> 4;
    float* wt = &ot[w][0];
    short8 Ah[4][2], Al[4][2];
#pragma unroll
    for (int rt = 0; rt < 4; ++rt)
#pragma unroll
        for (int c = 0; c < 2; ++c) {
            size_t off = ((size_t)((rg * 4 + rt) * 2 + c) * 64 + lane) * 8;
            Ah[rt][c] = *(const short8*)(ahi + off);
            Al[rt][c] = *(const short8*)(alo + off);
        }
    float br[4][4], gv[4][4];
#pragma unroll
    for (int rt = 0; rt < 4; ++rt)
#pragma unroll
        for (int r = 0; r < 4; ++r) {
            int row = rg * 64 + rt * 16 + g * 4 + r;
            br[rt][r] = brow[row];
            gv[rt][r] = ginv[row];
        }
    int t0 = mblk * 64 + w * 16;
    short8 Bh0, Bh1, Bl0, Bl1;
    {
        size_t o = (size_t)t0 * 1024 + (size_t)lane * 8;
        Bh0 = *(const short8*)(bhi + o); Bh1 = *(const short8*)(bhi + o + 512);
        Bl0 = *(const short8*)(blo + o); Bl1 = *(const short8*)(blo + o + 512);
    }
#pragma unroll 2
    for (int ti = 0; ti < 16; ++ti) {
        int t = t0 + ti;
        int tn = t0 + ((ti < 15) ? ti + 1 : 15);
        size_t on = (size_t)tn * 1024 + (size_t)lane * 8;
        short8 nh0 = *(const short8*)(bhi + on);
        short8 nh1 = *(const short8*)(bhi + on + 512);
        short8 nl0 = *(const short8*)(blo + on);
        short8 nl1 = *(const short8*)(blo + on + 512);
#pragma unroll
        for (int rt = 0; rt < 4; ++rt) {
            f32x4 C = {0.f, 0.f, 0.f, 0.f};
            C = MFMA(Ah[rt][0], Bh0, C);
            C = MFMA(Ah[rt][1], Bh1, C);
            C = MFMA(Al[rt][0], Bh0, C);
            C = MFMA(Al[rt][1], Bh1, C);
            C = MFMA(Ah[rt][0], Bl0, C);
            C = MFMA(Ah[rt][1], Bl1, C);
#pragma unroll
            for (int r = 0; r < 4; ++r)
                wt[(rt * 16 + g * 4 + r) * 20 + (lane & 15)] =
                    EXP2F(C[r] - br[rt][r]) * gv[rt][r];
        }
        // wave-private LDS tile -> coalesced float4 nontemporal stores (4 per wave per ti)
#pragma unroll
        for (int j = 0; j < 4; ++j) {
            int rl = j * 16 + (lane >> 2);
            f32x4 v = *(const f32x4*)&wt[rl * 20 + (lane & 3) * 4];
            float* dst = out + (size_t)(rg * 64 + rl) * MM + (size_t)t * 16 + (lane & 3) * 4;
            __builtin_nontemporal_store(v, (f32x4*)dst);
        }
        Bh0 = nh0; Bh1 = nh1; Bl0 = nl0; Bl1 = nl1;
    }
}

extern "C" void kernel_launch(void* const* d_in, const int* in_sizes, int n_in,
                              void* d_out, int out_size, void* d_ws, size_t ws_size,
                              hipStream_t stream) {
    const float* S   = (const float*)d_in[0];  // [256][2048]
    const float* mem = (const float*)d_in[1];  // [65536][64]
    const float* Wk  = (const float*)d_in[2];  // [256][2048]
    const float* bk  = (const float*)d_in[3];  // [256]
    const float* Wb  = (const float*)d_in[4];  // [4][2048]
    const float* bb  = (const float*)d_in[5];  // [4]
    float* out = (float*)d_out;                // [1024][65536]

    // workspace layout (~21.5 MB, all segments 16B-aligned)
    float* WkT      = (float*)d_ws;                          // 2048*256
    float* kpart    = WkT   + (size_t)RR * KEYS;             // 8*256*256
    float* q_rm     = kpart + (size_t)8 * BB * KEYS;         // 1024*64
    float* psum     = q_rm  + (size_t)NROW * LL;             // 1024*256
    float* brow     = psum  + (size_t)NROW * 256;            // 1024
    float* ginv     = brow  + NROW;                          // 1024
    float* normpart = ginv  + NROW;                          // 512
    unsigned short* bhi = (unsigned short*)(normpart + 512); // 8192*512
    unsigned short* blo = bhi + (size_t)8192 * 512;
    unsigned short* ahi = blo + (size_t)8192 * 512;          // 128*512
    unsigned short* alo = ahi + (size_t)128 * 512;

    transpose_k<<<dim3(BB / 64, RR / 64), 256, 0, stream>>>(Wk, WkT, KEYS, RR);
    prep_mem   <<<512,         256, 0, stream>>>(mem, bhi, blo, normpart);
    k0_keys    <<<dim3(32, 8), 256, 0, stream>>>(S, WkT, kpart);
    k1_finalize<<<NROW,        256, 0, stream>>>(S, kpart, bk, Wb, bb, normpart, q_rm, brow);
    prep_a     <<<32,          256, 0, stream>>>(q_rm, ahi, alo);
    k2_mfma    <<<1024,        256, 0, stream>>>(bhi, blo, ahi, alo, brow, psum);
    k3_combine <<<NROW,        256, 0, stream>>>(psum, ginv);
    k4_mfma    <<<1024,        256, 0, stream>>>(bhi, blo, ahi, alo, brow, ginv, out);
}

// Round 3
// 367.236 us; speedup vs baseline: 1.0820x; 1.0772x over previous
//
#include <hip/hip_runtime.h>
#include <hip/hip_bf16.h>

// Problem constants (B,R,M,L,H) = (256, 2048, 65536, 64, 4)
#define BB   256
#define RR   2048
#define MM   65536
#define LL   64
#define HH   4
#define NROW 1024      // B*H rows
#define KEYS 256       // H*L

typedef float f32x4 __attribute__((ext_vector_type(4)));
typedef short short8 __attribute__((ext_vector_type(8)));

#define MFMA(A,B,C) __builtin_amdgcn_mfma_f32_16x16x32_bf16((A),(B),(C),0,0,0)
#define LOG2E 1.4426950408889634f
#define EXP2F(x) __builtin_amdgcn_exp2f(x)

// ---- bf16 round-nearest-even split helpers ----
__device__ __forceinline__ unsigned short bf16_rn(float x) {
    union { float f; unsigned int u; } v; v.f = x;
    unsigned int r = v.u + 0x7FFFu + ((v.u >> 16) & 1u);
    return (unsigned short)(r >> 16);
}
__device__ __forceinline__ float bf16_to_f(unsigned short h) {
    union { float f; unsigned int u; } v; v.u = ((unsigned int)h) << 16; return v.f;
}
__device__ __forceinline__ void split8_store(const float* x, unsigned short* hi, unsigned short* lo) {
    unsigned int ph[4], pl[4];
#pragma unroll
    for (int j = 0; j < 4; ++j) {
        unsigned short h0 = bf16_rn(x[2*j]),   l0 = bf16_rn(x[2*j]   - bf16_to_f(h0));
        unsigned short h1 = bf16_rn(x[2*j+1]), l1 = bf16_rn(x[2*j+1] - bf16_to_f(h1));
        ph[j] = (unsigned int)h0 | ((unsigned int)h1 << 16);
        pl[j] = (unsigned int)l0 | ((unsigned int)l1 << 16);
    }
    ((uint4*)hi)[0] = make_uint4(ph[0], ph[1], ph[2], ph[3]);
    ((uint4*)lo)[0] = make_uint4(pl[0], pl[1], pl[2], pl[3]);
}

// ---------------- generic 64x64 tiled transpose: out[c][r] = in[r][c] ----------------
__global__ __launch_bounds__(256) void transpose_k(const float* __restrict__ in,
                                                   float* __restrict__ out,
                                                   int NR, int NC) {
    __shared__ float t[64 * 65];
    int r0 = blockIdx.x * 64, c0 = blockIdx.y * 64;
    int lane = threadIdx.x & 63, w = threadIdx.x >> 6;
#pragma unroll
    for (int i = 0; i < 16; ++i) {
        int rr = i * 4 + w;
        t[lane * 65 + rr] = in[(size_t)(r0 + rr) * NC + c0 + lane];
    }
    __syncthreads();
#pragma unroll
    for (int i = 0; i < 16; ++i) {
        int cc = i * 4 + w;
        out[(size_t)(c0 + cc) * NR + r0 + lane] = t[cc * 65 + lane];
    }
}

// ---------------- fused: stage 128 mem rows in LDS (coalesced), emit MFMA B-fragments
//                  (hi/lo bf16 split) + per-block max row squared-norm ----------------
__global__ __launch_bounds__(256) void prep_mem(const float* __restrict__ mem,
                                                unsigned short* __restrict__ bhi,
                                                unsigned short* __restrict__ blo,
                                                float* __restrict__ normpart) {
    __shared__ float t[128 * 68];     // pad 68: keeps float4 alignment, spreads banks
    __shared__ float rowsq[128];
    int blk = blockIdx.x, tid = threadIdx.x;
    const f32x4* src = (const f32x4*)(mem + (size_t)blk * 128 * LL);
#pragma unroll
    for (int i = 0; i < 8; ++i) {
        int idx = i * 256 + tid;              // flat float4 index
        int row = idx >> 4, c4 = idx & 15;
        *(f32x4*)&t[row * 68 + c4 * 4] = src[idx];
    }
    __syncthreads();
    if (tid < 128) {
        const float* rp = t + tid * 68;
        float s = 0.f;
#pragma unroll
        for (int k = 0; k < 64; ++k) s = fmaf(rp[k], rp[k], s);
        rowsq[tid] = s;
    }
    __syncthreads();
    if (tid < 64) {
        float m = fmaxf(rowsq[tid], rowsq[tid + 64]);
#pragma unroll
        for (int off = 1; off < 64; off <<= 1) m = fmaxf(m, __shfl_xor(m, off, 64));
        if (tid == 0) normpart[blk] = m;
    }
#pragma unroll
    for (int i = 0; i < 4; ++i) {
        int slot = i * 256 + tid;
        int lane = slot & 63, frag_l = slot >> 6;   // frag_l 0..15
        int t_l = frag_l >> 1, c = frag_l & 1;
        int row = t_l * 16 + (lane & 15);
        int k0 = c * 32 + (lane >> 4) * 8;
        const float* p = t + row * 68 + k0;
        float x[8];
#pragma unroll
        for (int j = 0; j < 8; ++j) x[j] = p[j];
        size_t gslot = ((size_t)blk * 16 + frag_l) * 64 + lane;
        split8_store(x, bhi + gslot * 8, blo + gslot * 8);
    }
}

// ---------------- K0: split-k partial keys GEMM ----------------
__global__ __launch_bounds__(256) void k0_keys(const float* __restrict__ S,
                                               const float* __restrict__ WkT,
                                               float* __restrict__ kpart) {
    __shared__ float sl[8 * 256];
    int bg = blockIdx.x, kc = blockIdx.y, tid = threadIdx.x;
    int b0 = bg * 8;
#pragma unroll
    for (int bi = 0; bi < 8; ++bi)
        sl[bi * 256 + tid] = S[(size_t)(b0 + bi) * RR + kc * 256 + tid];
    __syncthreads();
    float acc[8] = {0,0,0,0,0,0,0,0};
    const float* wp = WkT + (size_t)kc * 256 * KEYS + tid;
#pragma unroll 4
    for (int kk = 0; kk < 256; ++kk) {
        float wv = wp[kk * KEYS];
#pragma unroll
        for (int bi = 0; bi < 8; ++bi)
            acc[bi] = fmaf(sl[bi * 256 + kk], wv, acc[bi]);
    }
    float* op = kpart + (size_t)kc * BB * KEYS + (size_t)b0 * KEYS + tid;
#pragma unroll
    for (int bi = 0; bi < 8; ++bi)
        op[bi * KEYS] = acc[bi];
}

// ---------------- K1: beta, key norm, q_rm = keys*beta*log2e/norm, brow = beta*maxnorm*log2e ----
__global__ __launch_bounds__(256) void k1_finalize(const float* __restrict__ S,
                                                   const float* __restrict__ kpart,
                                                   const float* __restrict__ bk,
                                                   const float* __restrict__ Wb,
                                                   const float* __restrict__ bb,
                                                   const float* __restrict__ normpart,
                                                   float* __restrict__ q_rm,
                                                   float* __restrict__ brow) {
    int bh = blockIdx.x, b = bh >> 2, h = bh & 3;
    int tid = threadIdx.x, lane = tid & 63, w = tid >> 6;
    float p = 0.f;
#pragma unroll
    for (int i = 0; i < 8; ++i) {
        int k = i * 256 + tid;
        p += S[(size_t)b * RR + k] * Wb[(size_t)h * RR + k];
    }
    float nm = fmaxf(normpart[tid], normpart[256 + tid]);   // 512 partials
#pragma unroll
    for (int off = 1; off < 64; off <<= 1) {
        p  += __shfl_xor(p, off, 64);
        nm  = fmaxf(nm, __shfl_xor(nm, off, 64));
    }
    __shared__ float red[4], redm[4];
    if (lane == 0) { red[w] = p; redm[w] = nm; }
    __syncthreads();
    if (tid < 64) {
        float beta = red[0] + red[1] + red[2] + red[3] + bb[h];
        beta = fmaxf(beta, 0.f);
        float maxn = sqrtf(fmaxf(fmaxf(redm[0], redm[1]), fmaxf(redm[2], redm[3])));
        float kv = bk[h * LL + lane];
#pragma unroll
        for (int c = 0; c < 8; ++c)
            kv += kpart[(size_t)c * BB * KEYS + (size_t)b * KEYS + h * LL + lane];
        float sq = kv * kv;
#pragma unroll
        for (int off = 1; off < 64; off <<= 1) sq += __shfl_xor(sq, off, 64);
        float scale = beta * LOG2E / sqrtf(sq);
        q_rm[(size_t)bh * LL + lane] = kv * scale;
        if (lane == 0) brow[bh] = beta * maxn * LOG2E;  // exact upper bound (Cauchy-Schwarz), log2 domain
    }
}

// ---------------- swizzle q into MFMA A-fragment order, hi/lo bf16 ----------------
__global__ __launch_bounds__(256) void prep_a(const float* __restrict__ q_rm,
                                              unsigned short* __restrict__ ahi,
                                              unsigned short* __restrict__ alo) {
    int gid = blockIdx.x * 256 + threadIdx.x;   // 0..8191
    int lane = gid & 63, frag = gid >> 6;       // frag 0..127
    int rtg = frag >> 1, c = frag & 1;
    int row = rtg * 16 + (lane & 15);
    int k0 = c * 32 + (lane >> 4) * 8;
    const float4* src = (const float4*)(q_rm + (size_t)row * LL + k0);
    float4 x0 = src[0], x1 = src[1];
    float x[8] = {x0.x, x0.y, x0.z, x0.w, x1.x, x1.y, x1.z, x1.w};
    split8_store(x, ahi + (size_t)gid * 8, alo + (size_t)gid * 8);
}

// XCD-chunked bijective swizzle for 1024 blocks (1024 % 8 == 0)
__device__ __forceinline__ void decode_wg(int bx, int& mblk, int& rg) {
    int wg = ((bx & 7) << 7) | (bx >> 3);
    mblk = wg >> 4; rg = wg & 15;
}

// ---------------- K2: split-bf16 MFMA dot + exp2(d - brow) partial row sums ----------
__global__ __launch_bounds__(256) void k2_mfma(const unsigned short* __restrict__ bhi,
                                               const unsigned short* __restrict__ blo,
                                               const unsigned short* __restrict__ ahi,
                                               const unsigned short* __restrict__ alo,
                                               const float* __restrict__ brow,
                                               float* __restrict__ psum) {
    int mblk, rg; decode_wg(blockIdx.x, mblk, rg);
    int tid = threadIdx.x, w = tid >> 6, lane = tid & 63;
    int g = lane >> 4;
    short8 Ah[4][2], Al[4][2];
#pragma unroll
    for (int rt = 0; rt < 4; ++rt)
#pragma unroll
        for (int c = 0; c < 2; ++c) {
            size_t off = ((size_t)((rg * 4 + rt) * 2 + c) * 64 + lane) * 8;
            Ah[rt][c] = *(const short8*)(ahi + off);
            Al[rt][c] = *(const short8*)(alo + off);
        }
    float br[4][4];
#pragma unroll
    for (int rt = 0; rt < 4; ++rt)
#pragma unroll
        for (int r = 0; r < 4; ++r)
            br[rt][r] = brow[rg * 64 + rt * 16 + g * 4 + r];
    float s[4][4] = {{0.f}};
    int t0 = mblk * 64 + w * 16;
    short8 Bh0, Bh1, Bl0, Bl1;
    {
        size_t o = (size_t)t0 * 1024 + (size_t)lane * 8;
        Bh0 = *(const short8*)(bhi + o); Bh1 = *(const short8*)(bhi + o + 512);
        Bl0 = *(const short8*)(blo + o); Bl1 = *(const short8*)(blo + o + 512);
    }
#pragma unroll 4
    for (int ti = 0; ti < 16; ++ti) {
        int tn = t0 + ((ti < 15) ? ti + 1 : 15);      // clamp: harmless re-load on last iter
        size_t on = (size_t)tn * 1024 + (size_t)lane * 8;
        short8 nh0 = *(const short8*)(bhi + on);
        short8 nh1 = *(const short8*)(bhi + on + 512);
        short8 nl0 = *(const short8*)(blo + on);
        short8 nl1 = *(const short8*)(blo + on + 512);
#pragma unroll
        for (int rt = 0; rt < 4; ++rt) {
            f32x4 C = {0.f, 0.f, 0.f, 0.f};
            C = MFMA(Ah[rt][0], Bh0, C);
            C = MFMA(Ah[rt][1], Bh1, C);
            C = MFMA(Al[rt][0], Bh0, C);
            C = MFMA(Al[rt][1], Bh1, C);
            C = MFMA(Ah[rt][0], Bl0, C);
            C = MFMA(Ah[rt][1], Bl1, C);
#pragma unroll
            for (int r = 0; r < 4; ++r)
                s[rt][r] += EXP2F(C[r] - br[rt][r]);
        }
        Bh0 = nh0; Bh1 = nh1; Bl0 = nl0; Bl1 = nl1;
    }
#pragma unroll
    for (int rt = 0; rt < 4; ++rt)
#pragma unroll
        for (int r = 0; r < 4; ++r) {
            float v = s[rt][r];
            v += __shfl_xor(v, 1, 64);
            v += __shfl_xor(v, 2, 64);
            v += __shfl_xor(v, 4, 64);
            v += __shfl_xor(v, 8, 64);
            s[rt][r] = v;
        }
    if ((lane & 15) == 0) {
        int col = mblk * 4 + w;
#pragma unroll
        for (int rt = 0; rt < 4; ++rt)
#pragma unroll
            for (int r = 0; r < 4; ++r) {
                int row = rg * 64 + rt * 16 + g * 4 + r;
                psum[(size_t)row * 256 + col] = s[rt][r];
            }
    }
}

// ---------------- K3: combine 256 partial sums per row -> 1/sum ----------------
__global__ __launch_bounds__(256) void k3_combine(const float* __restrict__ psum,
                                                  float* __restrict__ ginv) {
    int row = blockIdx.x, tid = threadIdx.x, lane = tid & 63, w = tid >> 6;
    float v = psum[(size_t)row * 256 + tid];
#pragma unroll
    for (int off = 1; off < 64; off <<= 1) v += __shfl_xor(v, off, 64);
    __shared__ float sm[4];
    if (lane == 0) sm[w] = v;
    __syncthreads();
    if (tid == 0) ginv[row] = 1.0f / (sm[0] + sm[1] + sm[2] + sm[3]);
}

// ---------------- K4: MFMA recompute; ti-PAIRS staged in wave-private LDS, then
//                  full-128B-line nontemporal dwordx4 stores (no partial-line RMW) ----
// LDS row stride 44 words: write phase 2-way bank alias (free), read phase spread,
// 44*4=176 B keeps every row 16B-aligned for ds_read_b128.
__global__ __launch_bounds__(256) void k4_mfma(const unsigned short* __restrict__ bhi,
                                               const unsigned short* __restrict__ blo,
                                               const unsigned short* __restrict__ ahi,
                                               const unsigned short* __restrict__ alo,
                                               const float* __restrict__ brow,
                                               const float* __restrict__ ginv,
                                               float* __restrict__ out) {
    __shared__ float ot[4][64 * 44];   // 11 KB per wave, wave-private (no barriers)
    int mblk, rg; decode_wg(blockIdx.x, mblk, rg);
    int tid = threadIdx.x, w = tid >> 6, lane = tid & 63;
    int g = lane >> 4;
    float* wt = &ot[w][0];
    short8 Ah[4][2], Al[4][2];
#pragma unroll
    for (int rt = 0; rt < 4; ++rt)
#pragma unroll
        for (int c = 0; c < 2; ++c) {
            size_t off = ((size_t)((rg * 4 + rt) * 2 + c) * 64 + lane) * 8;
            Ah[rt][c] = *(const short8*)(ahi + off);
            Al[rt][c] = *(const short8*)(alo + off);
        }
    float br[4][4], gv[4][4];
#pragma unroll
    for (int rt = 0; rt < 4; ++rt)
#pragma unroll
        for (int r = 0; r < 4; ++r) {
            int row = rg * 64 + rt * 16 + g * 4 + r;
            br[rt][r] = brow[row];
            gv[rt][r] = ginv[row];
        }
    int t0 = mblk * 64 + w * 16;
    short8 Bh0, Bh1, Bl0, Bl1;
    {
        size_t o = (size_t)t0 * 1024 + (size_t)lane * 8;
        Bh0 = *(const short8*)(bhi + o); Bh1 = *(const short8*)(bhi + o + 512);
        Bl0 = *(const short8*)(blo + o); Bl1 = *(const short8*)(blo + o + 512);
    }
    for (int p = 0; p < 8; ++p) {
#pragma unroll
        for (int hf = 0; hf < 2; ++hf) {
            int ti = p * 2 + hf;
            int tn = t0 + ((ti < 15) ? ti + 1 : 15);
            size_t on = (size_t)tn * 1024 + (size_t)lane * 8;
            short8 nh0 = *(const short8*)(bhi + on);
            short8 nh1 = *(const short8*)(bhi + on + 512);
            short8 nl0 = *(const short8*)(blo + on);
            short8 nl1 = *(const short8*)(blo + on + 512);
#pragma unroll
            for (int rt = 0; rt < 4; ++rt) {
                f32x4 C = {0.f, 0.f, 0.f, 0.f};
                C = MFMA(Ah[rt][0], Bh0, C);
                C = MFMA(Ah[rt][1], Bh1, C);
                C = MFMA(Al[rt][0], Bh0, C);
                C = MFMA(Al[rt][1], Bh1, C);
                C = MFMA(Ah[rt][0], Bl0, C);
                C = MFMA(Ah[rt][1], Bl1, C);
#pragma unroll
                for (int r = 0; r < 4; ++r)
                    wt[(rt * 16 + g * 4 + r) * 44 + hf * 16 + (lane & 15)] =
                        EXP2F(C[r] - br[rt][r]) * gv[rt][r];
            }
            Bh0 = nh0; Bh1 = nh1; Bl0 = nl0; Bl1 = nl1;
        }
        // store the 64x32 pair-tile: 8 lanes cover one row's 128 B -> full HBM lines
        size_t colbase = (size_t)(t0 + p * 2) * 16;
#pragma unroll
        for (int i = 0; i < 8; ++i) {
            int rl = i * 8 + (lane >> 3);
            f32x4 v = *(const f32x4*)&wt[rl * 44 + (lane & 7) * 4];
            float* dst = out + (size_t)(rg * 64 + rl) * MM + colbase + (size_t)(lane & 7) * 4;
            __builtin_nontemporal_store(v, (f32x4*)dst);
        }
    }
}

extern "C" void kernel_launch(void* const* d_in, const int* in_sizes, int n_in,
                              void* d_out, int out_size, void* d_ws, size_t ws_size,
                              hipStream_t stream) {
    const float* S   = (const float*)d_in[0];  // [256][2048]
    const float* mem = (const float*)d_in[1];  // [65536][64]
    const float* Wk  = (const float*)d_in[2];  // [256][2048]
    const float* bk  = (const float*)d_in[3];  // [256]
    const float* Wb  = (const float*)d_in[4];  // [4][2048]
    const float* bb  = (const float*)d_in[5];  // [4]
    float* out = (float*)d_out;                // [1024][65536]

    // workspace layout (~21.5 MB, all segments 16B-aligned)
    float* WkT      = (float*)d_ws;                          // 2048*256
    float* kpart    = WkT   + (size_t)RR * KEYS;             // 8*256*256
    float* q_rm     = kpart + (size_t)8 * BB * KEYS;         // 1024*64
    float* psum     = q_rm  + (size_t)NROW * LL;             // 1024*256
    float* brow     = psum  + (size_t)NROW * 256;            // 1024
    float* ginv     = brow  + NROW;                          // 1024
    float* normpart = ginv  + NROW;                          // 512
    unsigned short* bhi = (unsigned short*)(normpart + 512); // 8192*512
    unsigned short* blo = bhi + (size_t)8192 * 512;
    unsigned short* ahi = blo + (size_t)8192 * 512;          // 128*512
    unsigned short* alo = ahi + (size_t)128 * 512;

    transpose_k<<<dim3(BB / 64, RR / 64), 256, 0, stream>>>(Wk, WkT, KEYS, RR);
    prep_mem   <<<512,         256, 0, stream>>>(mem, bhi, blo, normpart);
    k0_keys    <<<dim3(32, 8), 256, 0, stream>>>(S, WkT, kpart);
    k1_finalize<<<NROW,        256, 0, stream>>>(S, kpart, bk, Wb, bb, normpart, q_rm, brow);
    prep_a     <<<32,          256, 0, stream>>>(q_rm, ahi, alo);
    k2_mfma    <<<1024,        256, 0, stream>>>(bhi, blo, ahi, alo, brow, psum);
    k3_combine <<<NROW,        256, 0, stream>>>(psum, ginv);
    k4_mfma    <<<1024,        256, 0, stream>>>(bhi, blo, ahi, alo, brow, ginv, out);
}

// Round 5
// 355.359 us; speedup vs baseline: 1.1182x; 1.0334x over previous
//
#include <hip/hip_runtime.h>
#include <hip/hip_bf16.h>

// Problem constants (B,R,M,L,H) = (256, 2048, 65536, 64, 4)
#define BB   256
#define RR   2048
#define MM   65536
#define LL   64
#define HH   4
#define NROW 1024      // B*H rows
#define KEYS 256       // H*L

typedef float f32x4 __attribute__((ext_vector_type(4)));
typedef short short8 __attribute__((ext_vector_type(8)));

#define MFMA(A,B,C) __builtin_amdgcn_mfma_f32_16x16x32_bf16((A),(B),(C),0,0,0)
#define LOG2E 1.4426950408889634f
#define EXP2F(x) __builtin_amdgcn_exp2f(x)

// ---- bf16 round-nearest-even split helpers ----
__device__ __forceinline__ unsigned short bf16_rn(float x) {
    union { float f; unsigned int u; } v; v.f = x;
    unsigned int r = v.u + 0x7FFFu + ((v.u >> 16) & 1u);
    return (unsigned short)(r >> 16);
}
__device__ __forceinline__ float bf16_to_f(unsigned short h) {
    union { float f; unsigned int u; } v; v.u = ((unsigned int)h) << 16; return v.f;
}
__device__ __forceinline__ void split8_store(const float* x, unsigned short* hi, unsigned short* lo) {
    unsigned int ph[4], pl[4];
#pragma unroll
    for (int j = 0; j < 4; ++j) {
        unsigned short h0 = bf16_rn(x[2*j]),   l0 = bf16_rn(x[2*j]   - bf16_to_f(h0));
        unsigned short h1 = bf16_rn(x[2*j+1]), l1 = bf16_rn(x[2*j+1] - bf16_to_f(h1));
        ph[j] = (unsigned int)h0 | ((unsigned int)h1 << 16);
        pl[j] = (unsigned int)l0 | ((unsigned int)l1 << 16);
    }
    ((uint4*)hi)[0] = make_uint4(ph[0], ph[1], ph[2], ph[3]);
    ((uint4*)lo)[0] = make_uint4(pl[0], pl[1], pl[2], pl[3]);
}

// ---------------- generic 64x64 tiled transpose: out[c][r] = in[r][c] ----------------
__global__ __launch_bounds__(256) void transpose_k(const float* __restrict__ in,
                                                   float* __restrict__ out,
                                                   int NR, int NC) {
    __shared__ float t[64 * 65];
    int r0 = blockIdx.x * 64, c0 = blockIdx.y * 64;
    int lane = threadIdx.x & 63, w = threadIdx.x >> 6;
#pragma unroll
    for (int i = 0; i < 16; ++i) {
        int rr = i * 4 + w;
        t[lane * 65 + rr] = in[(size_t)(r0 + rr) * NC + c0 + lane];
    }
    __syncthreads();
#pragma unroll
    for (int i = 0; i < 16; ++i) {
        int cc = i * 4 + w;
        out[(size_t)(c0 + cc) * NR + r0 + lane] = t[cc * 65 + lane];
    }
}

// ---------------- fused: stage 128 mem rows in LDS (coalesced), emit MFMA B-fragments
//                  (hi/lo bf16 split) + per-block max row squared-norm ----------------
__global__ __launch_bounds__(256) void prep_mem(const float* __restrict__ mem,
                                                unsigned short* __restrict__ bhi,
                                                unsigned short* __restrict__ blo,
                                                float* __restrict__ normpart) {
    __shared__ float t[128 * 68];     // pad 68: keeps float4 alignment, spreads banks
    __shared__ float rowsq[128];
    int blk = blockIdx.x, tid = threadIdx.x;
    const f32x4* src = (const f32x4*)(mem + (size_t)blk * 128 * LL);
#pragma unroll
    for (int i = 0; i < 8; ++i) {
        int idx = i * 256 + tid;              // flat float4 index
        int row = idx >> 4, c4 = idx & 15;
        *(f32x4*)&t[row * 68 + c4 * 4] = src[idx];
    }
    __syncthreads();
    if (tid < 128) {
        const float* rp = t + tid * 68;
        float s = 0.f;
#pragma unroll
        for (int k = 0; k < 64; ++k) s = fmaf(rp[k], rp[k], s);
        rowsq[tid] = s;
    }
    __syncthreads();
    if (tid < 64) {
        float m = fmaxf(rowsq[tid], rowsq[tid + 64]);
#pragma unroll
        for (int off = 1; off < 64; off <<= 1) m = fmaxf(m, __shfl_xor(m, off, 64));
        if (tid == 0) normpart[blk] = m;
    }
#pragma unroll
    for (int i = 0; i < 4; ++i) {
        int slot = i * 256 + tid;
        int lane = slot & 63, frag_l = slot >> 6;   // frag_l 0..15
        int t_l = frag_l >> 1, c = frag_l & 1;
        int row = t_l * 16 + (lane & 15);
        int k0 = c * 32 + (lane >> 4) * 8;
        const float* p = t + row * 68 + k0;
        float x[8];
#pragma unroll
        for (int j = 0; j < 8; ++j) x[j] = p[j];
        size_t gslot = ((size_t)blk * 16 + frag_l) * 64 + lane;
        split8_store(x, bhi + gslot * 8, blo + gslot * 8);
    }
}

// ---------------- K0: split-k partial keys GEMM ----------------
__global__ __launch_bounds__(256) void k0_keys(const float* __restrict__ S,
                                               const float* __restrict__ WkT,
                                               float* __restrict__ kpart) {
    __shared__ float sl[8 * 256];
    int bg = blockIdx.x, kc = blockIdx.y, tid = threadIdx.x;
    int b0 = bg * 8;
#pragma unroll
    for (int bi = 0; bi < 8; ++bi)
        sl[bi * 256 + tid] = S[(size_t)(b0 + bi) * RR + kc * 256 + tid];
    __syncthreads();
    float acc[8] = {0,0,0,0,0,0,0,0};
    const float* wp = WkT + (size_t)kc * 256 * KEYS + tid;
#pragma unroll 4
    for (int kk = 0; kk < 256; ++kk) {
        float wv = wp[kk * KEYS];
#pragma unroll
        for (int bi = 0; bi < 8; ++bi)
            acc[bi] = fmaf(sl[bi * 256 + kk], wv, acc[bi]);
    }
    float* op = kpart + (size_t)kc * BB * KEYS + (size_t)b0 * KEYS + tid;
#pragma unroll
    for (int bi = 0; bi < 8; ++bi)
        op[bi * KEYS] = acc[bi];
}

// ---------------- K1: beta, key norm, q_rm = keys*beta*log2e/norm, brow = beta*maxnorm*log2e ----
__global__ __launch_bounds__(256) void k1_finalize(const float* __restrict__ S,
                                                   const float* __restrict__ kpart,
                                                   const float* __restrict__ bk,
                                                   const float* __restrict__ Wb,
                                                   const float* __restrict__ bb,
                                                   const float* __restrict__ normpart,
                                                   float* __restrict__ q_rm,
                                                   float* __restrict__ brow) {
    int bh = blockIdx.x, b = bh >> 2, h = bh & 3;
    int tid = threadIdx.x, lane = tid & 63, w = tid >> 6;
    float p = 0.f;
#pragma unroll
    for (int i = 0; i < 8; ++i) {
        int k = i * 256 + tid;
        p += S[(size_t)b * RR + k] * Wb[(size_t)h * RR + k];
    }
    float nm = fmaxf(normpart[tid], normpart[256 + tid]);   // 512 partials
#pragma unroll
    for (int off = 1; off < 64; off <<= 1) {
        p  += __shfl_xor(p, off, 64);
        nm  = fmaxf(nm, __shfl_xor(nm, off, 64));
    }
    __shared__ float red[4], redm[4];
    if (lane == 0) { red[w] = p; redm[w] = nm; }
    __syncthreads();
    if (tid < 64) {
        float beta = red[0] + red[1] + red[2] + red[3] + bb[h];
        beta = fmaxf(beta, 0.f);
        float maxn = sqrtf(fmaxf(fmaxf(redm[0], redm[1]), fmaxf(redm[2], redm[3])));
        float kv = bk[h * LL + lane];
#pragma unroll
        for (int c = 0; c < 8; ++c)
            kv += kpart[(size_t)c * BB * KEYS + (size_t)b * KEYS + h * LL + lane];
        float sq = kv * kv;
#pragma unroll
        for (int off = 1; off < 64; off <<= 1) sq += __shfl_xor(sq, off, 64);
        float scale = beta * LOG2E / sqrtf(sq);
        q_rm[(size_t)bh * LL + lane] = kv * scale;
        if (lane == 0) brow[bh] = beta * maxn * LOG2E;  // exact upper bound (Cauchy-Schwarz), log2 domain
    }
}

// ---------------- swizzle q into MFMA A-fragment order, hi/lo bf16 ----------------
__global__ __launch_bounds__(256) void prep_a(const float* __restrict__ q_rm,
                                              unsigned short* __restrict__ ahi,
                                              unsigned short* __restrict__ alo) {
    int gid = blockIdx.x * 256 + threadIdx.x;   // 0..8191
    int lane = gid & 63, frag = gid >> 6;       // frag 0..127
    int rtg = frag >> 1, c = frag & 1;
    int row = rtg * 16 + (lane & 15);
    int k0 = c * 32 + (lane >> 4) * 8;
    const float4* src = (const float4*)(q_rm + (size_t)row * LL + k0);
    float4 x0 = src[0], x1 = src[1];
    float x[8] = {x0.x, x0.y, x0.z, x0.w, x1.x, x1.y, x1.z, x1.w};
    split8_store(x, ahi + (size_t)gid * 8, alo + (size_t)gid * 8);
}

// XCD-chunked bijective swizzle for 1024 blocks (1024 % 8 == 0)
__device__ __forceinline__ void decode_wg(int bx, int& mblk, int& rg) {
    int wg = ((bx & 7) << 7) | (bx >> 3);
    mblk = wg >> 4; rg = wg & 15;
}

// ---------------- K2: split-bf16 MFMA dot + exp2(d - brow) partial row sums ----------
__global__ __launch_bounds__(256) void k2_mfma(const unsigned short* __restrict__ bhi,
                                               const unsigned short* __restrict__ blo,
                                               const unsigned short* __restrict__ ahi,
                                               const unsigned short* __restrict__ alo,
                                               const float* __restrict__ brow,
                                               float* __restrict__ psum) {
    int mblk, rg; decode_wg(blockIdx.x, mblk, rg);
    int tid = threadIdx.x, w = tid >> 6, lane = tid & 63;
    int g = lane >> 4;
    short8 Ah[4][2], Al[4][2];
#pragma unroll
    for (int rt = 0; rt < 4; ++rt)
#pragma unroll
        for (int c = 0; c < 2; ++c) {
            size_t off = ((size_t)((rg * 4 + rt) * 2 + c) * 64 + lane) * 8;
            Ah[rt][c] = *(const short8*)(ahi + off);
            Al[rt][c] = *(const short8*)(alo + off);
        }
    float br[4][4];
#pragma unroll
    for (int rt = 0; rt < 4; ++rt)
#pragma unroll
        for (int r = 0; r < 4; ++r)
            br[rt][r] = brow[rg * 64 + rt * 16 + g * 4 + r];
    float s[4][4] = {{0.f}};
    int t0 = mblk * 64 + w * 16;
    short8 Bh0, Bh1, Bl0, Bl1;
    {
        size_t o = (size_t)t0 * 1024 + (size_t)lane * 8;
        Bh0 = *(const short8*)(bhi + o); Bh1 = *(const short8*)(bhi + o + 512);
        Bl0 = *(const short8*)(blo + o); Bl1 = *(const short8*)(blo + o + 512);
    }
#pragma unroll 4
    for (int ti = 0; ti < 16; ++ti) {
        int tn = t0 + ((ti < 15) ? ti + 1 : 15);      // clamp: harmless re-load on last iter
        size_t on = (size_t)tn * 1024 + (size_t)lane * 8;
        short8 nh0 = *(const short8*)(bhi + on);
        short8 nh1 = *(const short8*)(bhi + on + 512);
        short8 nl0 = *(const short8*)(blo + on);
        short8 nl1 = *(const short8*)(blo + on + 512);
#pragma unroll
        for (int rt = 0; rt < 4; ++rt) {
            f32x4 C = {0.f, 0.f, 0.f, 0.f};
            C = MFMA(Ah[rt][0], Bh0, C);
            C = MFMA(Ah[rt][1], Bh1, C);
            C = MFMA(Al[rt][0], Bh0, C);
            C = MFMA(Al[rt][1], Bh1, C);
            C = MFMA(Ah[rt][0], Bl0, C);
            C = MFMA(Ah[rt][1], Bl1, C);
#pragma unroll
            for (int r = 0; r < 4; ++r)
                s[rt][r] += EXP2F(C[r] - br[rt][r]);
        }
        Bh0 = nh0; Bh1 = nh1; Bl0 = nl0; Bl1 = nl1;
    }
#pragma unroll
    for (int rt = 0; rt < 4; ++rt)
#pragma unroll
        for (int r = 0; r < 4; ++r) {
            float v = s[rt][r];
            v += __shfl_xor(v, 1, 64);
            v += __shfl_xor(v, 2, 64);
            v += __shfl_xor(v, 4, 64);
            v += __shfl_xor(v, 8, 64);
            s[rt][r] = v;
        }
    if ((lane & 15) == 0) {
        int col = mblk * 4 + w;
#pragma unroll
        for (int rt = 0; rt < 4; ++rt)
#pragma unroll
            for (int r = 0; r < 4; ++r) {
                int row = rg * 64 + rt * 16 + g * 4 + r;
                psum[(size_t)row * 256 + col] = s[rt][r];
            }
    }
}

// ---------------- K3: combine 256 partial sums per row -> 1/sum ----------------
__global__ __launch_bounds__(256) void k3_combine(const float* __restrict__ psum,
                                                  float* __restrict__ ginv) {
    int row = blockIdx.x, tid = threadIdx.x, lane = tid & 63, w = tid >> 6;
    float v = psum[(size_t)row * 256 + tid];
#pragma unroll
    for (int off = 1; off < 64; off <<= 1) v += __shfl_xor(v, off, 64);
    __shared__ float sm[4];
    if (lane == 0) sm[w] = v;
    __syncthreads();
    if (tid == 0) ginv[row] = 1.0f / (sm[0] + sm[1] + sm[2] + sm[3]);
}

// ---------------- K4 v2: MFMA recompute; block = 16 rows x 4096 cols.
// Per 512-col chunk: compute into 16x516 LDS tile, then block-cooperative
// streaming stores: 2 KB contiguous per output row (full DRAM pages, no
// short scattered chunks -> no activate-bound write stream).
// Grid 1024 = 64 rg x 16 mblk, XCD-chunked: XCD i owns mblks {2i,2i+1};
// B-frag working set 2 MB per XCD -> L2-resident.
__global__ __launch_bounds__(256) void k4_mfma(const unsigned short* __restrict__ bhi,
                                               const unsigned short* __restrict__ blo,
                                               const unsigned short* __restrict__ ahi,
                                               const unsigned short* __restrict__ alo,
                                               const float* __restrict__ brow,
                                               const float* __restrict__ ginv,
                                               float* __restrict__ out) {
    __shared__ float ot[16 * 516];   // stride 516: write phase 2 lanes/bank (free)
    int bx = blockIdx.x;
    int wg = ((bx & 7) << 7) | (bx >> 3);
    int mblk = wg >> 6, rg = wg & 63;       // mblk 0..15 (4096 cols), rg 0..63 (16 rows)
    int tid = threadIdx.x, w = tid >> 6, lane = tid & 63;
    int g = lane >> 4;
    short8 Ah[2], Al[2];
#pragma unroll
    for (int c = 0; c < 2; ++c) {
        size_t off = ((size_t)(rg * 2 + c) * 64 + lane) * 8;
        Ah[c] = *(const short8*)(ahi + off);
        Al[c] = *(const short8*)(alo + off);
    }
    float br[4], gv[4];
#pragma unroll
    for (int r = 0; r < 4; ++r) {
        int row = rg * 16 + g * 4 + r;
        br[r] = brow[row];
        gv[r] = ginv[row];
    }
    // wave w's ti within chunk c: t = mblk*256 + c*32 + w*8 + k, k=0..7
    int tbase = mblk * 256 + w * 8;
    short8 Bh0, Bh1, Bl0, Bl1;
    {
        size_t o = (size_t)tbase * 1024 + (size_t)lane * 8;
        Bh0 = *(const short8*)(bhi + o); Bh1 = *(const short8*)(bhi + o + 512);
        Bl0 = *(const short8*)(blo + o); Bl1 = *(const short8*)(blo + o + 512);
    }
    for (int c = 0; c < 8; ++c) {
#pragma unroll
        for (int k = 0; k < 8; ++k) {
            int j = c * 8 + k;
            int jn = (j < 63) ? j + 1 : 63;                 // linear prefetch index
            int tn = tbase + (jn >> 3) * 32 + (jn & 7);
            size_t on = (size_t)tn * 1024 + (size_t)lane * 8;
            short8 nh0 = *(const short8*)(bhi + on);
            short8 nh1 = *(const short8*)(bhi + on + 512);
            short8 nl0 = *(const short8*)(blo + on);
            short8 nl1 = *(const short8*)(blo + on + 512);
            f32x4 C = {0.f, 0.f, 0.f, 0.f};
            C = MFMA(Ah[0], Bh0, C);
            C = MFMA(Ah[1], Bh1, C);
            C = MFMA(Al[0], Bh0, C);
            C = MFMA(Al[1], Bh1, C);
            C = MFMA(Ah[0], Bl0, C);
            C = MFMA(Ah[1], Bl1, C);
            int cbase = w * 128 + k * 16 + (lane & 15);
#pragma unroll
            for (int r = 0; r < 4; ++r)
                ot[(g * 4 + r) * 516 + cbase] = EXP2F(C[r] - br[r]) * gv[r];
            Bh0 = nh0; Bh1 = nh1; Bl0 = nl0; Bl1 = nl1;
        }
        __syncthreads();
        // cooperative store: 8 rounds, each writes 2 full rows x 2 KB contiguous
        size_t gbase = (size_t)mblk * 4096 + (size_t)c * 512;
#pragma unroll
        for (int i = 0; i < 8; ++i) {
            int flat = i * 256 + tid;
            int rl = flat >> 7, slot = flat & 127;
            f32x4 v = *(const f32x4*)&ot[rl * 516 + slot * 4];
            float* dst = out + (size_t)(rg * 16 + rl) * MM + gbase + (size_t)slot * 4;
            __builtin_nontemporal_store(v, (f32x4*)dst);
        }
        __syncthreads();
    }
}

extern "C" void kernel_launch(void* const* d_in, const int* in_sizes, int n_in,
                              void* d_out, int out_size, void* d_ws, size_t ws_size,
                              hipStream_t stream) {
    const float* S   = (const float*)d_in[0];  // [256][2048]
    const float* mem = (const float*)d_in[1];  // [65536][64]
    const float* Wk  = (const float*)d_in[2];  // [256][2048]
    const float* bk  = (const float*)d_in[3];  // [256]
    const float* Wb  = (const float*)d_in[4];  // [4][2048]
    const float* bb  = (const float*)d_in[5];  // [4]
    float* out = (float*)d_out;                // [1024][65536]

    // workspace layout (~21.5 MB, all segments 16B-aligned)
    float* WkT      = (float*)d_ws;                          // 2048*256
    float* kpart    = WkT   + (size_t)RR * KEYS;             // 8*256*256
    float* q_rm     = kpart + (size_t)8 * BB * KEYS;         // 1024*64
    float* psum     = q_rm  + (size_t)NROW * LL;             // 1024*256
    float* brow     = psum  + (size_t)NROW * 256;            // 1024
    float* ginv     = brow  + NROW;                          // 1024
    float* normpart = ginv  + NROW;                          // 512
    unsigned short* bhi = (unsigned short*)(normpart + 512); // 8192*512
    unsigned short* blo = bhi + (size_t)8192 * 512;
    unsigned short* ahi = blo + (size_t)8192 * 512;          // 128*512
    unsigned short* alo = ahi + (size_t)128 * 512;

    transpose_k<<<dim3(BB / 64, RR / 64), 256, 0, stream>>>(Wk, WkT, KEYS, RR);
    prep_mem   <<<512,         256, 0, stream>>>(mem, bhi, blo, normpart);
    k0_keys    <<<dim3(32, 8), 256, 0, stream>>>(S, WkT, kpart);
    k1_finalize<<<NROW,        256, 0, stream>>>(S, kpart, bk, Wb, bb, normpart, q_rm, brow);
    prep_a     <<<32,          256, 0, stream>>>(q_rm, ahi, alo);
    k2_mfma    <<<1024,        256, 0, stream>>>(bhi, blo, ahi, alo, brow, psum);
    k3_combine <<<NROW,        256, 0, stream>>>(psum, ginv);
    k4_mfma    <<<1024,        256, 0, stream>>>(bhi, blo, ahi, alo, brow, ginv, out);
}